// Round 13
// baseline (174.337 us; speedup 1.0000x reference)
//
#include <hip/hip_runtime.h>
#include <stdint.h>

// ---------------- types & helpers ----------------
typedef short sh4 __attribute__((ext_vector_type(4)));
typedef short short8 __attribute__((ext_vector_type(8)));
typedef float f32x4 __attribute__((ext_vector_type(4)));
typedef _Float16 half4 __attribute__((ext_vector_type(4)));
typedef _Float16 half8 __attribute__((ext_vector_type(8)));
typedef unsigned int uint2v __attribute__((ext_vector_type(2)));

__device__ __forceinline__ short f2h(float f) {
    _Float16 h = (_Float16)f;
    return __builtin_bit_cast(short, h);
}

__device__ __forceinline__ f32x4 mfma_k32(short8 a, short8 b, f32x4 c) {
    return __builtin_amdgcn_mfma_f32_16x16x32_f16(
        __builtin_bit_cast(half8, a), __builtin_bit_cast(half8, b), c, 0, 0, 0);
}
__device__ __forceinline__ f32x4 mfma_k16(half4 a, half4 b, f32x4 c) {
    return __builtin_amdgcn_mfma_f32_16x16x16f16(a, b, c, 0, 0, 0);
}
__device__ __forceinline__ unsigned int pkrtz(float a, float b) {
    return __builtin_bit_cast(unsigned int, __builtin_amdgcn_cvt_pkrtz(a, b));
}

// Problem constants: B=4, C=256, H=W=128 (PX=16384), inner=256, heads=8, c/head=32,
// patch=8 -> keys=256, conv K-dim = 256*64 = 16384.
// NOTE (r6): logit std ~4.6, row max ~25 -> per-row max subtraction REQUIRED.
// NOTE (r9-r11): f16 logit stash (pack logits with cvt_pkrtz, exp from stash)
// produces wrong results (bit-identical absmax 13.03 across 3 variants; pitch
// and denominator ruled out by bisection). DO NOT stash logits in f16 —
// k_attn must use the two-pass QK^T (recompute) structure below.

// ---------------- pack kernels: 64x64 fp32 tile transpose -> f16 ----------------
__device__ __forceinline__ void transpose64(const float* __restrict__ src,
                                            short* __restrict__ dst,
                                            int srcSlowStride, int dstRowStride) {
    __shared__ float tile[64][65];
    const int t = threadIdx.x;
#pragma unroll
    for (int i = 0; i < 16; ++i) {
        int idx = i * 256 + t;
        int fast = idx & 63, slow = idx >> 6;
        tile[slow][fast] = src[(long)slow * srcSlowStride + fast];
    }
    __syncthreads();
#pragma unroll
    for (int i = 0; i < 2; ++i) {
        int ch = i * 256 + t;
        int fast = ch >> 3, sg = ch & 7;
        short8 v;
#pragma unroll
        for (int j = 0; j < 8; ++j) v[j] = f2h(tile[sg * 8 + j][fast]);
        *(short8*)(dst + (long)fast * dstRowStride + sg * 8) = v;
    }
}

// x: [4][256][16384] fp32 (NCHW) -> xn: [4][16384][256] f16 (NHWC)
__global__ __launch_bounds__(256) void k_pack_x(const float* __restrict__ x,
                                                short* __restrict__ xn) {
    int bi = blockIdx.x;                 // 4096 = 4b * 256pxt * 4ct
    int ct = bi & 3, pxt = (bi >> 2) & 255, b = bi >> 10;
    const float* src = x + (((long)(b * 256 + ct * 64)) << 14) + (long)pxt * 64;
    short* dst = xn + (((long)(b << 14) + pxt * 64) * 256) + ct * 64;
    transpose64(src, dst, 16384, 256);
}

// Wk/Wv: [256][256][64] fp32 -> wp: [512][64][256] f16 (oc<256: k, else v), K order (dydx, c)
__global__ __launch_bounds__(256) void k_pack_w(const float* __restrict__ wk,
                                                const float* __restrict__ wv,
                                                short* __restrict__ wp) {
    int bi = blockIdx.x;                 // 2048 = 512oc * 4ct
    int ct = bi & 3, oc = bi >> 2;
    const float* base = (oc < 256) ? (wk + (long)oc * 16384) : (wv + (long)(oc - 256) * 16384);
    const float* src = base + ct * 4096; // + c0*64
    short* dst = wp + (long)oc * 16384 + ct * 64;
    transpose64(src, dst, 64, 256);
}

// Wq: [256][256] fp32 -> f16 (layout preserved: [oc][c])
__global__ __launch_bounds__(256) void k_pack_wq(const float* __restrict__ wq,
                                                 short* __restrict__ wqp) {
    int i = blockIdx.x * 256 + threadIdx.x; // grid 256 -> 65536
    wqp[i] = f2h(wq[i]);
}

// ---------------- K/V conv as GEMM (128x64 tile, 512 blocks, 2/CU) ----
// C[patch 1024][oc 512] = A[patch][k 16384] * B[k][oc]
// grid 512 = 8kc * 8pm * 8nb; block 256 thr (4 waves); Kchunk 2048 (32 x BK=64).
__global__ __launch_bounds__(256) void k_kv_gemm(const short* __restrict__ xn,
                                                 const short* __restrict__ wp,
                                                 float* __restrict__ part) {
    __shared__ short Al[128 * 64]; // rows 128B = 8 granules, swizzled
    __shared__ short Bl[64 * 64];
    int bid = blockIdx.x;                       // 512
    int wg = (bid & 7) * 64 + (bid >> 3);       // XCD-contiguous swizzle (512 = 8*64)
    int nb = wg & 7, pm = (wg >> 3) & 7, kc = wg >> 6;
    int t = threadIdx.x, l = t & 63, w = t >> 6;
    int wm = w >> 1, wn = w & 1;
    int low = l & 15, q = l >> 4;

    f32x4 acc[4][2];
#pragma unroll
    for (int mt = 0; mt < 4; ++mt)
#pragma unroll
        for (int nt = 0; nt < 2; ++nt) acc[mt][nt] = (f32x4){0.f, 0.f, 0.f, 0.f};

    for (int kk = 0; kk < 32; ++kk) {
        short8 va[4], vb[2];
#pragma unroll
        for (int i = 0; i < 4; ++i) {           // A: 1024 granules (128 rows x 8)
            int g = i * 256 + t;
            int row = g >> 3, lg = g & 7;
            int patch = pm * 128 + row;
            int kg = kc * 2048 + kk * 64 + lg * 8;
            int dydx = kg >> 8, cc = kg & 255;
            int bb = patch >> 8, pid = patch & 255;
            int ph = pid >> 4, pw = pid & 15;
            int px = (ph * 8 + (dydx >> 3)) * 128 + pw * 8 + (dydx & 7);
            va[i] = *(const short8*)(xn + ((long)(bb << 14) + px) * 256 + cc);
        }
#pragma unroll
        for (int i = 0; i < 2; ++i) {           // B: 512 granules (64 rows x 8)
            int g = i * 256 + t;
            int row = g >> 3, lg = g & 7;
            int oc = nb * 64 + row;
            int kg = kc * 2048 + kk * 64 + lg * 8;
            vb[i] = *(const short8*)(wp + (long)oc * 16384 + kg);
        }
#pragma unroll
        for (int i = 0; i < 4; ++i) {
            int g = i * 256 + t;
            int row = g >> 3, lg = g & 7;
            *(short8*)(Al + row * 64 + ((lg ^ (row & 7)) * 8)) = va[i];
        }
#pragma unroll
        for (int i = 0; i < 2; ++i) {
            int g = i * 256 + t;
            int row = g >> 3, lg = g & 7;
            *(short8*)(Bl + row * 64 + ((lg ^ (row & 7)) * 8)) = vb[i];
        }
        __syncthreads();
#pragma unroll
        for (int ks = 0; ks < 2; ++ks) {
            short8 af[4], bf[2];
#pragma unroll
            for (int mt = 0; mt < 4; ++mt) {
                int row = wm * 64 + mt * 16 + low;
                int lg = ks * 4 + q;
                af[mt] = *(const short8*)(Al + row * 64 + ((lg ^ (row & 7)) * 8));
            }
#pragma unroll
            for (int nt = 0; nt < 2; ++nt) {
                int row = wn * 32 + nt * 16 + low;
                int lg = ks * 4 + q;
                bf[nt] = *(const short8*)(Bl + row * 64 + ((lg ^ (row & 7)) * 8));
            }
#pragma unroll
            for (int mt = 0; mt < 4; ++mt)
#pragma unroll
                for (int nt = 0; nt < 2; ++nt)
                    acc[mt][nt] = mfma_k32(af[mt], bf[nt], acc[mt][nt]);
        }
        __syncthreads();
    }
    // D: row(patch) = q*4+r (+16mt+64wm+128pm), col(oc) = low (+16nt+32wn+64nb)
#pragma unroll
    for (int mt = 0; mt < 4; ++mt) {
        int patch = pm * 128 + wm * 64 + mt * 16 + q * 4;
#pragma unroll
        for (int nt = 0; nt < 2; ++nt) {
            int oc = nb * 64 + wn * 32 + nt * 16 + low;
#pragma unroll
            for (int r = 0; r < 4; ++r)
                part[((long)kc * 1024 + patch + r) * 512 + oc] = acc[mt][nt][r];
        }
    }
}

// reduce partials, add bias, pack k -> [b][h][key][c], v -> [b][h][c][key] (f16)
__global__ __launch_bounds__(256) void k_kv_fin(const float* __restrict__ part,
                                                const float* __restrict__ bk,
                                                const float* __restrict__ bv,
                                                short* __restrict__ kp,
                                                short* __restrict__ vp) {
    int idx = blockIdx.x * 256 + threadIdx.x;   // 524288 = 1024patch * 512oc
    int oc = idx & 511, patch = idx >> 9;
    float s = 0.f;
#pragma unroll
    for (int kc = 0; kc < 8; ++kc) s += part[(long)kc * 524288 + idx];
    int b = patch >> 8, key = patch & 255;
    if (oc < 256) {
        s += bk[oc];
        kp[(((long)(b * 8 + (oc & 7)) * 256) + key) * 32 + (oc >> 3)] = f2h(s);
    } else {
        int o = oc - 256;
        s += bv[o];
        vp[(((long)(b * 8 + (o & 7)) * 32) + (o >> 3)) * 256 + key] = f2h(s);
    }
}

// ---------------- Q conv (1x1) as GEMM (no staging LDS, D[px][oc]) -------
// A-frag = xn[px][c] (16B contiguous per lane), B-frag = wqp[oc][c] (L2-hot).
// grid 1024 = 4b * 256 tiles of 64px; block 256 thr = 4 waves; wave w owns
// oc in [64w, 64w+64). LDS only for the output transpose (32KB -> 4 blocks/CU).
// q stored as [b][h 8][px 16384][c 32] f16 (attention reads 16B per lane).
__global__ __launch_bounds__(256) void k_q_gemm(const short* __restrict__ xn,
                                                const short* __restrict__ wqp,
                                                const float* __restrict__ bq,
                                                short* __restrict__ qp) {
    __shared__ short Tb[64 * 256];  // 32 KB
    int bi = blockIdx.x;            // 1024 = 4b * 256 tiles
    int b = bi >> 8, tile = bi & 255;
    long px0 = (long)tile * 64;
    int t = threadIdx.x, l = t & 63, w = t >> 6;
    int low = l & 15, q = l >> 4;

    const short* xb = xn + (((long)(b << 14)) + px0) * 256;

    float bqv[4];
#pragma unroll
    for (int nt = 0; nt < 4; ++nt) bqv[nt] = bq[w * 64 + nt * 16 + low];

    f32x4 acc[4][4];   // [mt: px][nt: oc]
#pragma unroll
    for (int mt = 0; mt < 4; ++mt)
#pragma unroll
        for (int nt = 0; nt < 4; ++nt) acc[mt][nt] = (f32x4){0.f, 0.f, 0.f, 0.f};

#pragma unroll
    for (int kstep = 0; kstep < 8; ++kstep) {
        short8 af[4], bf[4];
#pragma unroll
        for (int mt = 0; mt < 4; ++mt)
            af[mt] = *(const short8*)(xb + (mt * 16 + low) * 256 + kstep * 32 + q * 8);
#pragma unroll
        for (int nt = 0; nt < 4; ++nt)
            bf[nt] = *(const short8*)(wqp + (w * 64 + nt * 16 + low) * 256 + kstep * 32 + q * 8);
#pragma unroll
        for (int mt = 0; mt < 4; ++mt)
#pragma unroll
            for (int nt = 0; nt < 4; ++nt)
                acc[mt][nt] = mfma_k32(af[mt], bf[nt], acc[mt][nt]);
    }
    // D: px = mt*16 + q*4 + r, oc = w*64 + nt*16 + low.
    // Tb[px][h 8][c 32] pitch 256 shorts; 16B-granule index XOR (px&7).
#pragma unroll
    for (int mt = 0; mt < 4; ++mt)
#pragma unroll
        for (int nt = 0; nt < 4; ++nt) {
            int oc = w * 64 + nt * 16 + low;
            int h8 = oc & 7, cc = oc >> 3;
            int gi = h8 * 4 + (cc >> 3);          // 16B granule 0..31 within row
#pragma unroll
            for (int r = 0; r < 4; ++r) {
                int px = mt * 16 + q * 4 + r;
                Tb[px * 256 + ((gi ^ (px & 7)) * 8) + (cc & 7)] =
                    f2h(acc[mt][nt][r] + bqv[nt]);
            }
        }
    __syncthreads();
#pragma unroll
    for (int i = 0; i < 8; ++i) {
        int g = i * 256 + t;            // 2048 chunks of 16B
        int pxl = g >> 5, g16 = g & 31; // g16 = hh*4 + oct
        int hh = g16 >> 2, oct = g16 & 3;
        short8 v = *(const short8*)(Tb + pxl * 256 + ((g16 ^ (pxl & 7)) * 8));
        *(short8*)(qp + (((long)(b * 8 + hh) * 16384) + px0 + pxl) * 32 + oct * 8) = v;
    }
}

// ---------------- fused attention (v9: fused nt pair, 256px/block) ----
// grid 2048 = 4b * 8h * 64 tiles of 256px; block 256 thr = 4 waves.
// K/V staged ONCE per 256 px (amortized 2x vs r12). Two sub-tiles (tt) of
// 128 px; within each, the nt pair is fused: every Kl/Vl LDS read feeds BOTH
// nt MFMA chains (halves LDS reads + address VALU, doubles MFMA ILP).
// Two-pass QK^T per r9-r11 note (f16 logit stash is forbidden).
__global__ __launch_bounds__(256) void k_attn(const short* __restrict__ qp,
                                              const short* __restrict__ kp,
                                              const short* __restrict__ vp,
                                              float* __restrict__ out) {
    __shared__ short Kl[256 * 32];   // 16 KB, straight copy of kp tile
    __shared__ short Vl[32 * 264];   // 16.9 KB
    int bi = blockIdx.x;
    int tile = bi & 63, h = (bi >> 6) & 7, b = bi >> 9;
    int bh = b * 8 + h;
    long px0 = (long)tile * 256;
    int t = threadIdx.x, l = t & 63, w = t >> 6;
    int low = l & 15, q = l >> 4;

    const short* kbase = kp + (long)bh * 8192;    // [key 256][c 32]
    const short* vbase = vp + (long)bh * 8192;    // [c 32][key 256]
    const short* qbase = qp + (long)bh * 16384 * 32;  // [px][c 32]

    // stage K -> LDS (straight 16KB copy, coalesced)
#pragma unroll
    for (int i = 0; i < 4; ++i) {
        int g = i * 256 + t;
        *(short8*)(Kl + g * 8) = *(const short8*)(kbase + g * 8);
    }
    // stage V -> LDS (pitch 264)
#pragma unroll
    for (int i = 0; i < 4; ++i) {
        int g = i * 256 + t;
        int c = g >> 5, k8 = g & 31;
        *(short8*)(Vl + c * 264 + k8 * 8) = *(const short8*)(vbase + c * 256 + k8 * 8);
    }
    __syncthreads();

#pragma unroll 1
    for (int tt = 0; tt < 2; ++tt) {
        long pxb = px0 + tt * 128 + w * 32 + low;   // nt=0 px; nt=1 is +16
        short8 bq0 = *(const short8*)(qbase + pxb * 32 + q * 8);
        short8 bq1 = *(const short8*)(qbase + (pxb + 16) * 32 + q * 8);

        // pass 1: row max for both nt, shared Kl reads
        float m0 = -1e30f, m1 = -1e30f;
#pragma unroll
        for (int mt = 0; mt < 16; ++mt) {
            short8 ak = *(const short8*)(Kl + (mt * 16 + low) * 32 + q * 8);
            f32x4 d0 = mfma_k32(ak, bq0, (f32x4){0.f, 0.f, 0.f, 0.f});
            f32x4 d1 = mfma_k32(ak, bq1, (f32x4){0.f, 0.f, 0.f, 0.f});
            m0 = fmaxf(m0, fmaxf(fmaxf(d0[0], d0[1]), fmaxf(d0[2], d0[3])));
            m1 = fmaxf(m1, fmaxf(fmaxf(d1[0], d1[1]), fmaxf(d1[2], d1[3])));
        }
        m0 = fmaxf(m0, __shfl_xor(m0, 16));
        m0 = fmaxf(m0, __shfl_xor(m0, 32));
        m1 = fmaxf(m1, __shfl_xor(m1, 16));
        m1 = fmaxf(m1, __shfl_xor(m1, 32));

        // pass 2: recompute, exp, pack, sum — both nt, shared Kl reads
        float s0 = 0.f, s1 = 0.f;
        uint2v pk0[16], pk1[16];
#pragma unroll
        for (int mt = 0; mt < 16; ++mt) {
            short8 ak = *(const short8*)(Kl + (mt * 16 + low) * 32 + q * 8);
            f32x4 d0 = mfma_k32(ak, bq0, (f32x4){0.f, 0.f, 0.f, 0.f});
            f32x4 d1 = mfma_k32(ak, bq1, (f32x4){0.f, 0.f, 0.f, 0.f});
            float a0 = __expf(d0[0] - m0), a1 = __expf(d0[1] - m0);
            float a2 = __expf(d0[2] - m0), a3 = __expf(d0[3] - m0);
            float b0 = __expf(d1[0] - m1), b1 = __expf(d1[1] - m1);
            float b2 = __expf(d1[2] - m1), b3 = __expf(d1[3] - m1);
            s0 += (a0 + a1) + (a2 + a3);
            s1 += (b0 + b1) + (b2 + b3);
            pk0[mt][0] = pkrtz(a0, a1);
            pk0[mt][1] = pkrtz(a2, a3);
            pk1[mt][0] = pkrtz(b0, b1);
            pk1[mt][1] = pkrtz(b2, b3);
        }
        s0 += __shfl_xor(s0, 16);
        s0 += __shfl_xor(s0, 32);
        s1 += __shfl_xor(s1, 16);
        s1 += __shfl_xor(s1, 32);
        float inv0 = 1.0f / s0, inv1 = 1.0f / s1;

        // PV: both nt share Vl reads
        f32x4 o0[2], o1[2];
        o0[0] = (f32x4){0.f, 0.f, 0.f, 0.f};
        o0[1] = (f32x4){0.f, 0.f, 0.f, 0.f};
        o1[0] = (f32x4){0.f, 0.f, 0.f, 0.f};
        o1[1] = (f32x4){0.f, 0.f, 0.f, 0.f};
        __builtin_amdgcn_s_setprio(1);
#pragma unroll
        for (int kc = 0; kc < 16; ++kc) {
            half4 pb0 = __builtin_bit_cast(half4, pk0[kc]);
            half4 pb1 = __builtin_bit_cast(half4, pk1[kc]);
#pragma unroll
            for (int ct = 0; ct < 2; ++ct) {
                half4 av = __builtin_bit_cast(half4,
                    *(const sh4*)(Vl + (ct * 16 + low) * 264 + kc * 16 + q * 4));
                o0[ct] = mfma_k16(av, pb0, o0[ct]);
                o1[ct] = mfma_k16(av, pb1, o1[ct]);
            }
        }
        __builtin_amdgcn_s_setprio(0);

        // write out [b][c*8+h][px] fp32; D row=c=ct*16+q*4+r, col=px
#pragma unroll
        for (int ct = 0; ct < 2; ++ct)
#pragma unroll
            for (int r = 0; r < 4; ++r) {
                int c = ct * 16 + q * 4 + r;
                long base = ((long)(b * 256 + c * 8 + h)) << 14;
                out[base + pxb]      = o0[ct][r] * inv0;
                out[base + pxb + 16] = o1[ct][r] * inv1;
            }
    }
}

// ---------------- launch ----------------
extern "C" void kernel_launch(void* const* d_in, const int* in_sizes, int n_in,
                              void* d_out, int out_size, void* d_ws, size_t ws_size,
                              hipStream_t stream) {
    const float* x  = (const float*)d_in[0];
    const float* Wq = (const float*)d_in[1];
    const float* bq = (const float*)d_in[2];
    const float* Wk = (const float*)d_in[3];
    const float* bk = (const float*)d_in[4];
    const float* Wv = (const float*)d_in[5];
    const float* bv = (const float*)d_in[6];
    float* out = (float*)d_out;

    char* ws = (char*)d_ws;
    const size_t OFF_XN = 0;             // 33,554,432  x NHWC f16
    const size_t OFF_Q  = 33554432;      // 33,554,432  q [b][h][px][c] f16
    const size_t OFF_WP = 67108864;      // 16,777,216  w_pack [512][16384] f16
    const size_t OFF_WQ = 83886080;      //    131,072  wq f16
    const size_t OFF_KP = 84017152;      //    524,288  k_pack f16
    const size_t OFF_VP = 84541440;      //    524,288  v_pack f16
    const size_t OFF_PT = 85065728;      // 16,777,216  partials fp32 [8][1024][512]
    const size_t NEEDED = 118620160;
    if (ws_size < NEEDED) return;        // fail loudly via validation

    short* xn  = (short*)(ws + OFF_XN);
    short* qp  = (short*)(ws + OFF_Q);
    short* wp  = (short*)(ws + OFF_WP);
    short* wqp = (short*)(ws + OFF_WQ);
    short* kp  = (short*)(ws + OFF_KP);
    short* vp  = (short*)(ws + OFF_VP);
    float* part= (float*)(ws + OFF_PT);

    k_pack_x <<<dim3(4096), dim3(256), 0, stream>>>(x, xn);
    k_pack_w <<<dim3(2048), dim3(256), 0, stream>>>(Wk, Wv, wp);
    k_pack_wq<<<dim3(256),  dim3(256), 0, stream>>>(Wq, wqp);
    k_kv_gemm<<<dim3(512),  dim3(256), 0, stream>>>(xn, wp, part);
    k_kv_fin <<<dim3(2048), dim3(256), 0, stream>>>(part, bk, bv, kp, vp);
    k_q_gemm <<<dim3(1024), dim3(256), 0, stream>>>(xn, wqp, bq, qp);
    k_attn   <<<dim3(2048), dim3(256), 0, stream>>>(qp, kp, vp, out);
}

// Round 15
// 155.490 us; speedup vs baseline: 1.1212x; 1.1212x over previous
//
#include <hip/hip_runtime.h>
#include <stdint.h>

// ---------------- types & helpers ----------------
typedef short sh4 __attribute__((ext_vector_type(4)));
typedef short short8 __attribute__((ext_vector_type(8)));
typedef float f32x4 __attribute__((ext_vector_type(4)));
typedef _Float16 half4 __attribute__((ext_vector_type(4)));
typedef _Float16 half8 __attribute__((ext_vector_type(8)));
typedef unsigned int uint2v __attribute__((ext_vector_type(2)));

__device__ __forceinline__ short f2h(float f) {
    _Float16 h = (_Float16)f;
    return __builtin_bit_cast(short, h);
}

__device__ __forceinline__ f32x4 mfma_k32(short8 a, short8 b, f32x4 c) {
    return __builtin_amdgcn_mfma_f32_16x16x32_f16(
        __builtin_bit_cast(half8, a), __builtin_bit_cast(half8, b), c, 0, 0, 0);
}
__device__ __forceinline__ f32x4 mfma_k16(half4 a, half4 b, f32x4 c) {
    return __builtin_amdgcn_mfma_f32_16x16x16f16(a, b, c, 0, 0, 0);
}
__device__ __forceinline__ unsigned int pkrtz(float a, float b) {
    return __builtin_bit_cast(unsigned int, __builtin_amdgcn_cvt_pkrtz(a, b));
}

// Problem constants: B=4, C=256, H=W=128 (PX=16384), inner=256, heads=8, c/head=32,
// patch=8 -> keys=256, conv K-dim = 256*64 = 16384.
// NOTE (r6): a shift within ~10 of the row max is REQUIRED before exp when P is
//   packed to f16 (overflow above, subnormal-flush below).
// NOTE (r14): Cauchy-Schwarz bound M=||q||*max||k|| is ~20 ABOVE the row max for
//   weakly-correlated q,k -> all P flush to zero in f16 -> all-zero output.
//   Norm-product bounds are too loose; the max must come from the logits.
// NOTE (r9-r11): f16 logit stash (pack logits, exp from stash) -> wrong results
//   (bisected). exp must run on the f32 MFMA outputs; hence TWO-PASS QK^T.
// NOTE (r13): fusing the nt pair (both pk arrays live) -> VGPR 156, occupancy
//   halved, net regression. Keep nt iterations strictly sequential.

// ---------------- pack kernels: 64x64 fp32 tile transpose -> f16 ----------------
__device__ __forceinline__ void transpose64(const float* __restrict__ src,
                                            short* __restrict__ dst,
                                            int srcSlowStride, int dstRowStride) {
    __shared__ float tile[64][65];
    const int t = threadIdx.x;
#pragma unroll
    for (int i = 0; i < 16; ++i) {
        int idx = i * 256 + t;
        int fast = idx & 63, slow = idx >> 6;
        tile[slow][fast] = src[(long)slow * srcSlowStride + fast];
    }
    __syncthreads();
#pragma unroll
    for (int i = 0; i < 2; ++i) {
        int ch = i * 256 + t;
        int fast = ch >> 3, sg = ch & 7;
        short8 v;
#pragma unroll
        for (int j = 0; j < 8; ++j) v[j] = f2h(tile[sg * 8 + j][fast]);
        *(short8*)(dst + (long)fast * dstRowStride + sg * 8) = v;
    }
}

// x: [4][256][16384] fp32 (NCHW) -> xn: [4][16384][256] f16 (NHWC)
__global__ __launch_bounds__(256) void k_pack_x(const float* __restrict__ x,
                                                short* __restrict__ xn) {
    int bi = blockIdx.x;                 // 4096 = 4b * 256pxt * 4ct
    int ct = bi & 3, pxt = (bi >> 2) & 255, b = bi >> 10;
    const float* src = x + (((long)(b * 256 + ct * 64)) << 14) + (long)pxt * 64;
    short* dst = xn + (((long)(b << 14) + pxt * 64) * 256) + ct * 64;
    transpose64(src, dst, 16384, 256);
}

// Wk/Wv: [256][256][64] fp32 -> wp: [512][64][256] f16 (oc<256: k, else v), K order (dydx, c)
__global__ __launch_bounds__(256) void k_pack_w(const float* __restrict__ wk,
                                                const float* __restrict__ wv,
                                                short* __restrict__ wp) {
    int bi = blockIdx.x;                 // 2048 = 512oc * 4ct
    int ct = bi & 3, oc = bi >> 2;
    const float* base = (oc < 256) ? (wk + (long)oc * 16384) : (wv + (long)(oc - 256) * 16384);
    const float* src = base + ct * 4096; // + c0*64
    short* dst = wp + (long)oc * 16384 + ct * 64;
    transpose64(src, dst, 64, 256);
}

// Wq: [256][256] fp32 -> f16 (layout preserved: [oc][c])
__global__ __launch_bounds__(256) void k_pack_wq(const float* __restrict__ wq,
                                                 short* __restrict__ wqp) {
    int i = blockIdx.x * 256 + threadIdx.x; // grid 256 -> 65536
    wqp[i] = f2h(wq[i]);
}

// ---------------- K/V conv as GEMM (128x64 tile, 512 blocks, 2/CU) ----
// C[patch 1024][oc 512] = A[patch][k 16384] * B[k][oc]
// grid 512 = 8kc * 8pm * 8nb; block 256 thr (4 waves); Kchunk 2048 (32 x BK=64).
__global__ __launch_bounds__(256) void k_kv_gemm(const short* __restrict__ xn,
                                                 const short* __restrict__ wp,
                                                 float* __restrict__ part) {
    __shared__ short Al[128 * 64]; // rows 128B = 8 granules, swizzled
    __shared__ short Bl[64 * 64];
    int bid = blockIdx.x;                       // 512
    int wg = (bid & 7) * 64 + (bid >> 3);       // XCD-contiguous swizzle (512 = 8*64)
    int nb = wg & 7, pm = (wg >> 3) & 7, kc = wg >> 6;
    int t = threadIdx.x, l = t & 63, w = t >> 6;
    int wm = w >> 1, wn = w & 1;
    int low = l & 15, q = l >> 4;

    f32x4 acc[4][2];
#pragma unroll
    for (int mt = 0; mt < 4; ++mt)
#pragma unroll
        for (int nt = 0; nt < 2; ++nt) acc[mt][nt] = (f32x4){0.f, 0.f, 0.f, 0.f};

    for (int kk = 0; kk < 32; ++kk) {
        short8 va[4], vb[2];
#pragma unroll
        for (int i = 0; i < 4; ++i) {           // A: 1024 granules (128 rows x 8)
            int g = i * 256 + t;
            int row = g >> 3, lg = g & 7;
            int patch = pm * 128 + row;
            int kg = kc * 2048 + kk * 64 + lg * 8;
            int dydx = kg >> 8, cc = kg & 255;
            int bb = patch >> 8, pid = patch & 255;
            int ph = pid >> 4, pw = pid & 15;
            int px = (ph * 8 + (dydx >> 3)) * 128 + pw * 8 + (dydx & 7);
            va[i] = *(const short8*)(xn + ((long)(bb << 14) + px) * 256 + cc);
        }
#pragma unroll
        for (int i = 0; i < 2; ++i) {           // B: 512 granules (64 rows x 8)
            int g = i * 256 + t;
            int row = g >> 3, lg = g & 7;
            int oc = nb * 64 + row;
            int kg = kc * 2048 + kk * 64 + lg * 8;
            vb[i] = *(const short8*)(wp + (long)oc * 16384 + kg);
        }
#pragma unroll
        for (int i = 0; i < 4; ++i) {
            int g = i * 256 + t;
            int row = g >> 3, lg = g & 7;
            *(short8*)(Al + row * 64 + ((lg ^ (row & 7)) * 8)) = va[i];
        }
#pragma unroll
        for (int i = 0; i < 2; ++i) {
            int g = i * 256 + t;
            int row = g >> 3, lg = g & 7;
            *(short8*)(Bl + row * 64 + ((lg ^ (row & 7)) * 8)) = vb[i];
        }
        __syncthreads();
#pragma unroll
        for (int ks = 0; ks < 2; ++ks) {
            short8 af[4], bf[2];
#pragma unroll
            for (int mt = 0; mt < 4; ++mt) {
                int row = wm * 64 + mt * 16 + low;
                int lg = ks * 4 + q;
                af[mt] = *(const short8*)(Al + row * 64 + ((lg ^ (row & 7)) * 8));
            }
#pragma unroll
            for (int nt = 0; nt < 2; ++nt) {
                int row = wn * 32 + nt * 16 + low;
                int lg = ks * 4 + q;
                bf[nt] = *(const short8*)(Bl + row * 64 + ((lg ^ (row & 7)) * 8));
            }
#pragma unroll
            for (int mt = 0; mt < 4; ++mt)
#pragma unroll
                for (int nt = 0; nt < 2; ++nt)
                    acc[mt][nt] = mfma_k32(af[mt], bf[nt], acc[mt][nt]);
        }
        __syncthreads();
    }
    // D: row(patch) = q*4+r (+16mt+64wm+128pm), col(oc) = low (+16nt+32wn+64nb)
#pragma unroll
    for (int mt = 0; mt < 4; ++mt) {
        int patch = pm * 128 + wm * 64 + mt * 16 + q * 4;
#pragma unroll
        for (int nt = 0; nt < 2; ++nt) {
            int oc = nb * 64 + wn * 32 + nt * 16 + low;
#pragma unroll
            for (int r = 0; r < 4; ++r)
                part[((long)kc * 1024 + patch + r) * 512 + oc] = acc[mt][nt][r];
        }
    }
}

// reduce partials, add bias, pack k -> [b][h][key][c], v -> [b][h][c][key] (f16)
__global__ __launch_bounds__(256) void k_kv_fin(const float* __restrict__ part,
                                                const float* __restrict__ bk,
                                                const float* __restrict__ bv,
                                                short* __restrict__ kp,
                                                short* __restrict__ vp) {
    int idx = blockIdx.x * 256 + threadIdx.x;   // 524288 = 1024patch * 512oc
    int oc = idx & 511, patch = idx >> 9;
    float s = 0.f;
#pragma unroll
    for (int kc = 0; kc < 8; ++kc) s += part[(long)kc * 524288 + idx];
    int b = patch >> 8, key = patch & 255;
    if (oc < 256) {
        s += bk[oc];
        kp[(((long)(b * 8 + (oc & 7)) * 256) + key) * 32 + (oc >> 3)] = f2h(s);
    } else {
        int o = oc - 256;
        s += bv[o];
        vp[(((long)(b * 8 + (o & 7)) * 32) + (o >> 3)) * 256 + key] = f2h(s);
    }
}

// ---------------- Q conv (1x1) as GEMM (no staging LDS, D[px][oc]) -------
// A-frag = xn[px][c] (16B contiguous per lane), B-frag = wqp[oc][c] (L2-hot).
// grid 1024 = 4b * 256 tiles of 64px; block 256 thr = 4 waves; wave w owns
// oc in [64w, 64w+64). LDS only for the output transpose (32KB -> 4 blocks/CU).
// q stored as [b][h 8][px 16384][c 32] f16 (attention reads 16B per lane).
__global__ __launch_bounds__(256) void k_q_gemm(const short* __restrict__ xn,
                                                const short* __restrict__ wqp,
                                                const float* __restrict__ bq,
                                                short* __restrict__ qp) {
    __shared__ short Tb[64 * 256];  // 32 KB
    int bi = blockIdx.x;            // 1024 = 4b * 256 tiles
    int b = bi >> 8, tile = bi & 255;
    long px0 = (long)tile * 64;
    int t = threadIdx.x, l = t & 63, w = t >> 6;
    int low = l & 15, q = l >> 4;

    const short* xb = xn + (((long)(b << 14)) + px0) * 256;

    float bqv[4];
#pragma unroll
    for (int nt = 0; nt < 4; ++nt) bqv[nt] = bq[w * 64 + nt * 16 + low];

    f32x4 acc[4][4];   // [mt: px][nt: oc]
#pragma unroll
    for (int mt = 0; mt < 4; ++mt)
#pragma unroll
        for (int nt = 0; nt < 4; ++nt) acc[mt][nt] = (f32x4){0.f, 0.f, 0.f, 0.f};

#pragma unroll
    for (int kstep = 0; kstep < 8; ++kstep) {
        short8 af[4], bf[4];
#pragma unroll
        for (int mt = 0; mt < 4; ++mt)
            af[mt] = *(const short8*)(xb + (mt * 16 + low) * 256 + kstep * 32 + q * 8);
#pragma unroll
        for (int nt = 0; nt < 4; ++nt)
            bf[nt] = *(const short8*)(wqp + (w * 64 + nt * 16 + low) * 256 + kstep * 32 + q * 8);
#pragma unroll
        for (int mt = 0; mt < 4; ++mt)
#pragma unroll
            for (int nt = 0; nt < 4; ++nt)
                acc[mt][nt] = mfma_k32(af[mt], bf[nt], acc[mt][nt]);
    }
    // D: px = mt*16 + q*4 + r, oc = w*64 + nt*16 + low.
    // Tb[px][h 8][c 32] pitch 256 shorts; 16B-granule index XOR (px&7).
#pragma unroll
    for (int mt = 0; mt < 4; ++mt)
#pragma unroll
        for (int nt = 0; nt < 4; ++nt) {
            int oc = w * 64 + nt * 16 + low;
            int h8 = oc & 7, cc = oc >> 3;
            int gi = h8 * 4 + (cc >> 3);          // 16B granule 0..31 within row
#pragma unroll
            for (int r = 0; r < 4; ++r) {
                int px = mt * 16 + q * 4 + r;
                Tb[px * 256 + ((gi ^ (px & 7)) * 8) + (cc & 7)] =
                    f2h(acc[mt][nt][r] + bqv[nt]);
            }
        }
    __syncthreads();
#pragma unroll
    for (int i = 0; i < 8; ++i) {
        int g = i * 256 + t;            // 2048 chunks of 16B
        int pxl = g >> 5, g16 = g & 31; // g16 = hh*4 + oct
        int hh = g16 >> 2, oct = g16 & 3;
        short8 v = *(const short8*)(Tb + pxl * 256 + ((g16 ^ (pxl & 7)) * 8));
        *(short8*)(qp + (((long)(b * 8 + hh) * 16384) + px0 + pxl) * 32 + oct * 8) = v;
    }
}

// ---------------- fused attention (v11: r12 two-pass arithmetic, 256px/block) ----
// grid 2048 = 4b * 8h * 64 tiles of 256px; block 256 thr = 4 waves x 64 px.
// K/V staged ONCE per 256 px (2x amortization vs r12). nt = 4 strictly
// sequential iterations of r12's verified two-pass body (exact row max,
// exp on f32 MFMA outputs, per-lane sum + shfl). setprio around PV (T5).
__global__ __launch_bounds__(256) void k_attn(const short* __restrict__ qp,
                                              const short* __restrict__ kp,
                                              const short* __restrict__ vp,
                                              float* __restrict__ out) {
    __shared__ short Kl[256 * 32];   // 16 KB, straight copy of kp tile
    __shared__ short Vl[32 * 264];   // 16.9 KB
    int bi = blockIdx.x;
    int tile = bi & 63, h = (bi >> 6) & 7, b = bi >> 9;
    int bh = b * 8 + h;
    long px0 = (long)tile * 256;
    int t = threadIdx.x, l = t & 63, w = t >> 6;
    int low = l & 15, q = l >> 4;

    const short* kbase = kp + (long)bh * 8192;    // [key 256][c 32]
    const short* vbase = vp + (long)bh * 8192;    // [c 32][key 256]
    const short* qbase = qp + (long)bh * 16384 * 32;  // [px][c 32]

    // stage K -> LDS (straight 16KB copy, coalesced)
#pragma unroll
    for (int i = 0; i < 4; ++i) {
        int g = i * 256 + t;
        *(short8*)(Kl + g * 8) = *(const short8*)(kbase + g * 8);
    }
    // stage V -> LDS (pitch 264)
#pragma unroll
    for (int i = 0; i < 4; ++i) {
        int g = i * 256 + t;
        int c = g >> 5, k8 = g & 31;
        *(short8*)(Vl + c * 264 + k8 * 8) = *(const short8*)(vbase + c * 256 + k8 * 8);
    }
    __syncthreads();

#pragma unroll 1
    for (int nt = 0; nt < 4; ++nt) {
        long px = px0 + w * 64 + nt * 16 + low;
        // q B-frag: 16B contiguous (k = c = q*8+j)
        short8 bq2 = *(const short8*)(qbase + px * 32 + q * 8);

        // pass 1: exact row max (d dies each iteration -> no 64-VGPR array)
        float m = -1e30f;
#pragma unroll
        for (int mt = 0; mt < 16; ++mt) {
            short8 ak = *(const short8*)(Kl + (mt * 16 + low) * 32 + q * 8);
            f32x4 d = mfma_k32(ak, bq2, (f32x4){0.f, 0.f, 0.f, 0.f});
            m = fmaxf(m, fmaxf(fmaxf(d[0], d[1]), fmaxf(d[2], d[3])));
        }
        m = fmaxf(m, __shfl_xor(m, 16));
        m = fmaxf(m, __shfl_xor(m, 32));

        // pass 2: recompute, exp on f32 outputs, pack, sum
        float s = 0.f;
        uint2v pk[16];
#pragma unroll
        for (int mt = 0; mt < 16; ++mt) {
            short8 ak = *(const short8*)(Kl + (mt * 16 + low) * 32 + q * 8);
            f32x4 d = mfma_k32(ak, bq2, (f32x4){0.f, 0.f, 0.f, 0.f});
            float p0 = __expf(d[0] - m);
            float p1 = __expf(d[1] - m);
            float p2 = __expf(d[2] - m);
            float p3 = __expf(d[3] - m);
            s += (p0 + p1) + (p2 + p3);
            pk[mt][0] = pkrtz(p0, p1);
            pk[mt][1] = pkrtz(p2, p3);
        }
        s += __shfl_xor(s, 16);
        s += __shfl_xor(s, 32);
        float inv = 1.0f / s;

        // PV: o2[ct] = sum_kc V^T[c][16keys] x P[16keys][px]  (16x16x16)
        f32x4 o2[2];
        o2[0] = (f32x4){0.f, 0.f, 0.f, 0.f};
        o2[1] = (f32x4){0.f, 0.f, 0.f, 0.f};
        __builtin_amdgcn_s_setprio(1);
#pragma unroll
        for (int kc = 0; kc < 16; ++kc) {
            half4 pb = __builtin_bit_cast(half4, pk[kc]);
#pragma unroll
            for (int ct = 0; ct < 2; ++ct) {
                half4 av = __builtin_bit_cast(half4,
                    *(const sh4*)(Vl + (ct * 16 + low) * 264 + kc * 16 + q * 4));
                o2[ct] = mfma_k16(av, pb, o2[ct]);
            }
        }
        __builtin_amdgcn_s_setprio(0);
        // write out [b][c*8+h][px] fp32; D row=c=ct*16+q*4+r, col=px
#pragma unroll
        for (int ct = 0; ct < 2; ++ct)
#pragma unroll
            for (int r = 0; r < 4; ++r) {
                int c = ct * 16 + q * 4 + r;
                out[(((long)(b * 256 + c * 8 + h)) << 14) + px] = o2[ct][r] * inv;
            }
    }
}

// ---------------- launch ----------------
extern "C" void kernel_launch(void* const* d_in, const int* in_sizes, int n_in,
                              void* d_out, int out_size, void* d_ws, size_t ws_size,
                              hipStream_t stream) {
    const float* x  = (const float*)d_in[0];
    const float* Wq = (const float*)d_in[1];
    const float* bq = (const float*)d_in[2];
    const float* Wk = (const float*)d_in[3];
    const float* bk = (const float*)d_in[4];
    const float* Wv = (const float*)d_in[5];
    const float* bv = (const float*)d_in[6];
    float* out = (float*)d_out;

    char* ws = (char*)d_ws;
    const size_t OFF_XN = 0;             // 33,554,432  x NHWC f16
    const size_t OFF_Q  = 33554432;      // 33,554,432  q [b][h][px][c] f16
    const size_t OFF_WP = 67108864;      // 16,777,216  w_pack [512][16384] f16
    const size_t OFF_WQ = 83886080;      //    131,072  wq f16
    const size_t OFF_KP = 84017152;      //    524,288  k_pack f16
    const size_t OFF_VP = 84541440;      //    524,288  v_pack f16
    const size_t OFF_PT = 85065728;      // 16,777,216  partials fp32 [8][1024][512]
    const size_t NEEDED = 118620160;
    if (ws_size < NEEDED) return;        // fail loudly via validation

    short* xn  = (short*)(ws + OFF_XN);
    short* qp  = (short*)(ws + OFF_Q);
    short* wp  = (short*)(ws + OFF_WP);
    short* wqp = (short*)(ws + OFF_WQ);
    short* kp  = (short*)(ws + OFF_KP);
    short* vp  = (short*)(ws + OFF_VP);
    float* part= (float*)(ws + OFF_PT);

    k_pack_x <<<dim3(4096), dim3(256), 0, stream>>>(x, xn);
    k_pack_w <<<dim3(2048), dim3(256), 0, stream>>>(Wk, Wv, wp);
    k_pack_wq<<<dim3(256),  dim3(256), 0, stream>>>(Wq, wqp);
    k_kv_gemm<<<dim3(512),  dim3(256), 0, stream>>>(xn, wp, part);
    k_kv_fin <<<dim3(2048), dim3(256), 0, stream>>>(part, bk, bv, kp, vp);
    k_q_gemm <<<dim3(1024), dim3(256), 0, stream>>>(xn, wqp, bq, qp);
    k_attn   <<<dim3(2048), dim3(256), 0, stream>>>(qp, kp, vp, out);
}

// Round 16
// 154.605 us; speedup vs baseline: 1.1276x; 1.0057x over previous
//
#include <hip/hip_runtime.h>
#include <stdint.h>

// ---------------- types & helpers ----------------
typedef short sh4 __attribute__((ext_vector_type(4)));
typedef short short8 __attribute__((ext_vector_type(8)));
typedef float f32x4 __attribute__((ext_vector_type(4)));
typedef _Float16 half4 __attribute__((ext_vector_type(4)));
typedef _Float16 half8 __attribute__((ext_vector_type(8)));
typedef unsigned int uint2v __attribute__((ext_vector_type(2)));

__device__ __forceinline__ short f2h(float f) {
    _Float16 h = (_Float16)f;
    return __builtin_bit_cast(short, h);
}

__device__ __forceinline__ f32x4 mfma_k32(short8 a, short8 b, f32x4 c) {
    return __builtin_amdgcn_mfma_f32_16x16x32_f16(
        __builtin_bit_cast(half8, a), __builtin_bit_cast(half8, b), c, 0, 0, 0);
}
__device__ __forceinline__ f32x4 mfma_k16(half4 a, half4 b, f32x4 c) {
    return __builtin_amdgcn_mfma_f32_16x16x16f16(a, b, c, 0, 0, 0);
}
__device__ __forceinline__ unsigned int pkrtz(float a, float b) {
    return __builtin_bit_cast(unsigned int, __builtin_amdgcn_cvt_pkrtz(a, b));
}
__device__ __forceinline__ float exp2_raw(float x) {
    float r;
    asm("v_exp_f32 %0, %1" : "=v"(r) : "v"(x));   // 2^x, single instr
    return r;
}

// Problem constants: B=4, C=256, H=W=128 (PX=16384), inner=256, heads=8, c/head=32,
// patch=8 -> keys=256, conv K-dim = 256*64 = 16384.
// NOTE (r6/r14): the exp shift must come from the logits themselves (exact row
//   max); norm-product upper bounds are ~20 too loose -> f16 P flushes to 0.
// NOTE (r9-r11): f16 logit stash -> wrong results (bisected). exp must run on
//   f32 MFMA outputs; hence TWO-PASS QK^T.
// NOTE (r9 vs r10): ones-row MFMA denominator and shfl-sum denominator gave
//   BIT-IDENTICAL outputs on identical P -> ones-row denominator is correct;
//   the r9 failure was the stash. Ones-row is used below (VALU -> MFMA shift).
// NOTE (r13): keeping both nt P-arrays live -> VGPR 156, occupancy halved.
//   Keep nt iterations strictly sequential.
// NOTE (r16): q is PRE-SCALED by log2(e) in k_q_gemm so softmax uses raw
//   v_exp_f32 (2^x) with no per-element multiply. qp is consumed ONLY by k_attn.

// ---------------- pack kernels: 64x64 fp32 tile transpose -> f16 ----------------
__device__ __forceinline__ void transpose64(const float* __restrict__ src,
                                            short* __restrict__ dst,
                                            int srcSlowStride, int dstRowStride) {
    __shared__ float tile[64][65];
    const int t = threadIdx.x;
#pragma unroll
    for (int i = 0; i < 16; ++i) {
        int idx = i * 256 + t;
        int fast = idx & 63, slow = idx >> 6;
        tile[slow][fast] = src[(long)slow * srcSlowStride + fast];
    }
    __syncthreads();
#pragma unroll
    for (int i = 0; i < 2; ++i) {
        int ch = i * 256 + t;
        int fast = ch >> 3, sg = ch & 7;
        short8 v;
#pragma unroll
        for (int j = 0; j < 8; ++j) v[j] = f2h(tile[sg * 8 + j][fast]);
        *(short8*)(dst + (long)fast * dstRowStride + sg * 8) = v;
    }
}

// x: [4][256][16384] fp32 (NCHW) -> xn: [4][16384][256] f16 (NHWC)
__global__ __launch_bounds__(256) void k_pack_x(const float* __restrict__ x,
                                                short* __restrict__ xn) {
    int bi = blockIdx.x;                 // 4096 = 4b * 256pxt * 4ct
    int ct = bi & 3, pxt = (bi >> 2) & 255, b = bi >> 10;
    const float* src = x + (((long)(b * 256 + ct * 64)) << 14) + (long)pxt * 64;
    short* dst = xn + (((long)(b << 14) + pxt * 64) * 256) + ct * 64;
    transpose64(src, dst, 16384, 256);
}

// Wk/Wv: [256][256][64] fp32 -> wp: [512][64][256] f16 (oc<256: k, else v), K order (dydx, c)
__global__ __launch_bounds__(256) void k_pack_w(const float* __restrict__ wk,
                                                const float* __restrict__ wv,
                                                short* __restrict__ wp) {
    int bi = blockIdx.x;                 // 2048 = 512oc * 4ct
    int ct = bi & 3, oc = bi >> 2;
    const float* base = (oc < 256) ? (wk + (long)oc * 16384) : (wv + (long)(oc - 256) * 16384);
    const float* src = base + ct * 4096; // + c0*64
    short* dst = wp + (long)oc * 16384 + ct * 64;
    transpose64(src, dst, 64, 256);
}

// Wq: [256][256] fp32 -> f16 (layout preserved: [oc][c])
__global__ __launch_bounds__(256) void k_pack_wq(const float* __restrict__ wq,
                                                 short* __restrict__ wqp) {
    int i = blockIdx.x * 256 + threadIdx.x; // grid 256 -> 65536
    wqp[i] = f2h(wq[i]);
}

// ---------------- K/V conv as GEMM (128x64 tile, 512 blocks, 2/CU) ----
// C[patch 1024][oc 512] = A[patch][k 16384] * B[k][oc]
// grid 512 = 8kc * 8pm * 8nb; block 256 thr (4 waves); Kchunk 2048 (32 x BK=64).
__global__ __launch_bounds__(256) void k_kv_gemm(const short* __restrict__ xn,
                                                 const short* __restrict__ wp,
                                                 float* __restrict__ part) {
    __shared__ short Al[128 * 64]; // rows 128B = 8 granules, swizzled
    __shared__ short Bl[64 * 64];
    int bid = blockIdx.x;                       // 512
    int wg = (bid & 7) * 64 + (bid >> 3);       // XCD-contiguous swizzle (512 = 8*64)
    int nb = wg & 7, pm = (wg >> 3) & 7, kc = wg >> 6;
    int t = threadIdx.x, l = t & 63, w = t >> 6;
    int wm = w >> 1, wn = w & 1;
    int low = l & 15, q = l >> 4;

    f32x4 acc[4][2];
#pragma unroll
    for (int mt = 0; mt < 4; ++mt)
#pragma unroll
        for (int nt = 0; nt < 2; ++nt) acc[mt][nt] = (f32x4){0.f, 0.f, 0.f, 0.f};

    for (int kk = 0; kk < 32; ++kk) {
        short8 va[4], vb[2];
#pragma unroll
        for (int i = 0; i < 4; ++i) {           // A: 1024 granules (128 rows x 8)
            int g = i * 256 + t;
            int row = g >> 3, lg = g & 7;
            int patch = pm * 128 + row;
            int kg = kc * 2048 + kk * 64 + lg * 8;
            int dydx = kg >> 8, cc = kg & 255;
            int bb = patch >> 8, pid = patch & 255;
            int ph = pid >> 4, pw = pid & 15;
            int px = (ph * 8 + (dydx >> 3)) * 128 + pw * 8 + (dydx & 7);
            va[i] = *(const short8*)(xn + ((long)(bb << 14) + px) * 256 + cc);
        }
#pragma unroll
        for (int i = 0; i < 2; ++i) {           // B: 512 granules (64 rows x 8)
            int g = i * 256 + t;
            int row = g >> 3, lg = g & 7;
            int oc = nb * 64 + row;
            int kg = kc * 2048 + kk * 64 + lg * 8;
            vb[i] = *(const short8*)(wp + (long)oc * 16384 + kg);
        }
#pragma unroll
        for (int i = 0; i < 4; ++i) {
            int g = i * 256 + t;
            int row = g >> 3, lg = g & 7;
            *(short8*)(Al + row * 64 + ((lg ^ (row & 7)) * 8)) = va[i];
        }
#pragma unroll
        for (int i = 0; i < 2; ++i) {
            int g = i * 256 + t;
            int row = g >> 3, lg = g & 7;
            *(short8*)(Bl + row * 64 + ((lg ^ (row & 7)) * 8)) = vb[i];
        }
        __syncthreads();
#pragma unroll
        for (int ks = 0; ks < 2; ++ks) {
            short8 af[4], bf[2];
#pragma unroll
            for (int mt = 0; mt < 4; ++mt) {
                int row = wm * 64 + mt * 16 + low;
                int lg = ks * 4 + q;
                af[mt] = *(const short8*)(Al + row * 64 + ((lg ^ (row & 7)) * 8));
            }
#pragma unroll
            for (int nt = 0; nt < 2; ++nt) {
                int row = wn * 32 + nt * 16 + low;
                int lg = ks * 4 + q;
                bf[nt] = *(const short8*)(Bl + row * 64 + ((lg ^ (row & 7)) * 8));
            }
#pragma unroll
            for (int mt = 0; mt < 4; ++mt)
#pragma unroll
                for (int nt = 0; nt < 2; ++nt)
                    acc[mt][nt] = mfma_k32(af[mt], bf[nt], acc[mt][nt]);
        }
        __syncthreads();
    }
    // D: row(patch) = q*4+r (+16mt+64wm+128pm), col(oc) = low (+16nt+32wn+64nb)
#pragma unroll
    for (int mt = 0; mt < 4; ++mt) {
        int patch = pm * 128 + wm * 64 + mt * 16 + q * 4;
#pragma unroll
        for (int nt = 0; nt < 2; ++nt) {
            int oc = nb * 64 + wn * 32 + nt * 16 + low;
#pragma unroll
            for (int r = 0; r < 4; ++r)
                part[((long)kc * 1024 + patch + r) * 512 + oc] = acc[mt][nt][r];
        }
    }
}

// reduce partials, add bias, pack k -> [b][h][key][c], v -> [b][h][c][key] (f16)
__global__ __launch_bounds__(256) void k_kv_fin(const float* __restrict__ part,
                                                const float* __restrict__ bk,
                                                const float* __restrict__ bv,
                                                short* __restrict__ kp,
                                                short* __restrict__ vp) {
    int idx = blockIdx.x * 256 + threadIdx.x;   // 524288 = 1024patch * 512oc
    int oc = idx & 511, patch = idx >> 9;
    float s = 0.f;
#pragma unroll
    for (int kc = 0; kc < 8; ++kc) s += part[(long)kc * 524288 + idx];
    int b = patch >> 8, key = patch & 255;
    if (oc < 256) {
        s += bk[oc];
        kp[(((long)(b * 8 + (oc & 7)) * 256) + key) * 32 + (oc >> 3)] = f2h(s);
    } else {
        int o = oc - 256;
        s += bv[o];
        vp[(((long)(b * 8 + (o & 7)) * 32) + (o >> 3)) * 256 + key] = f2h(s);
    }
}

// ---------------- Q conv (1x1) as GEMM (no staging LDS, D[px][oc]) -------
// A-frag = xn[px][c], B-frag = wqp[oc][c] (L2-hot). grid 1024; 4 waves.
// q stored as [b][h 8][px 16384][c 32] f16, PRE-SCALED by log2(e) (r16 note).
__global__ __launch_bounds__(256) void k_q_gemm(const short* __restrict__ xn,
                                                const short* __restrict__ wqp,
                                                const float* __restrict__ bq,
                                                short* __restrict__ qp) {
    __shared__ short Tb[64 * 256];  // 32 KB
    int bi = blockIdx.x;            // 1024 = 4b * 256 tiles
    int b = bi >> 8, tile = bi & 255;
    long px0 = (long)tile * 64;
    int t = threadIdx.x, l = t & 63, w = t >> 6;
    int low = l & 15, q = l >> 4;

    const short* xb = xn + (((long)(b << 14)) + px0) * 256;

    float bqv[4];
#pragma unroll
    for (int nt = 0; nt < 4; ++nt) bqv[nt] = bq[w * 64 + nt * 16 + low];

    f32x4 acc[4][4];   // [mt: px][nt: oc]
#pragma unroll
    for (int mt = 0; mt < 4; ++mt)
#pragma unroll
        for (int nt = 0; nt < 4; ++nt) acc[mt][nt] = (f32x4){0.f, 0.f, 0.f, 0.f};

#pragma unroll
    for (int kstep = 0; kstep < 8; ++kstep) {
        short8 af[4], bf[4];
#pragma unroll
        for (int mt = 0; mt < 4; ++mt)
            af[mt] = *(const short8*)(xb + (mt * 16 + low) * 256 + kstep * 32 + q * 8);
#pragma unroll
        for (int nt = 0; nt < 4; ++nt)
            bf[nt] = *(const short8*)(wqp + (w * 64 + nt * 16 + low) * 256 + kstep * 32 + q * 8);
#pragma unroll
        for (int mt = 0; mt < 4; ++mt)
#pragma unroll
            for (int nt = 0; nt < 4; ++nt)
                acc[mt][nt] = mfma_k32(af[mt], bf[nt], acc[mt][nt]);
    }
    // D: px = mt*16 + q*4 + r, oc = w*64 + nt*16 + low.
    // Tb[px][h 8][c 32] pitch 256 shorts; 16B-granule index XOR (px&7).
    const float LOG2E = 1.44269504088896f;
#pragma unroll
    for (int mt = 0; mt < 4; ++mt)
#pragma unroll
        for (int nt = 0; nt < 4; ++nt) {
            int oc = w * 64 + nt * 16 + low;
            int h8 = oc & 7, cc = oc >> 3;
            int gi = h8 * 4 + (cc >> 3);          // 16B granule 0..31 within row
#pragma unroll
            for (int r = 0; r < 4; ++r) {
                int px = mt * 16 + q * 4 + r;
                Tb[px * 256 + ((gi ^ (px & 7)) * 8) + (cc & 7)] =
                    f2h((acc[mt][nt][r] + bqv[nt]) * LOG2E);
            }
        }
    __syncthreads();
#pragma unroll
    for (int i = 0; i < 8; ++i) {
        int g = i * 256 + t;            // 2048 chunks of 16B
        int pxl = g >> 5, g16 = g & 31; // g16 = hh*4 + oct
        int hh = g16 >> 2, oct = g16 & 3;
        short8 v = *(const short8*)(Tb + pxl * 256 + ((g16 ^ (pxl & 7)) * 8));
        *(short8*)(qp + (((long)(b * 8 + hh) * 16384) + px0 + pxl) * 32 + oct * 8) = v;
    }
}

// ---------------- fused attention (v12: exp2-direct, ones-row denom) ----
// grid 2048 = 4b * 8h * 64 tiles of 256px; block 256 thr = 4 waves x 64 px.
// Two-pass QK^T (r9-r11 note). Logits arrive log2e-scaled -> raw v_exp_f32.
// Denominator via ones-row MFMA (r9==r10 bit-identity proves equivalence).
// LDS bases hoisted so all Kl/Vl reads use compile-time offsets.
__global__ __launch_bounds__(256) void k_attn(const short* __restrict__ qp,
                                              const short* __restrict__ kp,
                                              const short* __restrict__ vp,
                                              float* __restrict__ out) {
    __shared__ short Kl[256 * 32];   // 16 KB, straight copy of kp tile
    __shared__ short Vl[32 * 264];   // 16.9 KB
    int bi = blockIdx.x;
    int tile = bi & 63, h = (bi >> 6) & 7, b = bi >> 9;
    int bh = b * 8 + h;
    long px0 = (long)tile * 256;
    int t = threadIdx.x, l = t & 63, w = t >> 6;
    int low = l & 15, q = l >> 4;

    const short* kbase = kp + (long)bh * 8192;    // [key 256][c 32]
    const short* vbase = vp + (long)bh * 8192;    // [c 32][key 256]
    const short* qbase = qp + (long)bh * 16384 * 32;  // [px][c 32]

    // stage K -> LDS (straight 16KB copy, coalesced)
#pragma unroll
    for (int i = 0; i < 4; ++i) {
        int g = i * 256 + t;
        *(short8*)(Kl + g * 8) = *(const short8*)(kbase + g * 8);
    }
    // stage V -> LDS (pitch 264)
#pragma unroll
    for (int i = 0; i < 4; ++i) {
        int g = i * 256 + t;
        int c = g >> 5, k8 = g & 31;
        *(short8*)(Vl + c * 264 + k8 * 8) = *(const short8*)(vbase + c * 256 + k8 * 8);
    }
    __syncthreads();

    const short* kA = Kl + low * 32 + q * 8;   // + mt*512 (imm offset)
    const short* vA = Vl + low * 264 + q * 4;  // + ct*4224 + kc*16 (imm offset)
    const sh4 sone = {0x3C00, 0x3C00, 0x3C00, 0x3C00};
    const half4 vones = __builtin_bit_cast(half4, sone);

#pragma unroll 1
    for (int nt = 0; nt < 4; ++nt) {
        long px = px0 + w * 64 + nt * 16 + low;
        // q B-frag: 16B contiguous (k = c = q*8+j); values log2e-scaled
        short8 bq2 = *(const short8*)(qbase + px * 32 + q * 8);

        // pass 1: exact row max (pairwise fmax -> v_max3-fusable)
        float m = -1e30f;
#pragma unroll
        for (int mt = 0; mt < 16; ++mt) {
            short8 ak = *(const short8*)(kA + mt * 512);
            f32x4 d = mfma_k32(ak, bq2, (f32x4){0.f, 0.f, 0.f, 0.f});
            m = fmaxf(fmaxf(d[0], d[1]), m);
            m = fmaxf(fmaxf(d[2], d[3]), m);
        }
        m = fmaxf(m, __shfl_xor(m, 16));
        m = fmaxf(m, __shfl_xor(m, 32));

        // pass 2: recompute, 2^x directly (no mul), pack P to f16
        uint2v pk[16];
#pragma unroll
        for (int mt = 0; mt < 16; ++mt) {
            short8 ak = *(const short8*)(kA + mt * 512);
            f32x4 d = mfma_k32(ak, bq2, (f32x4){0.f, 0.f, 0.f, 0.f});
            float p0 = exp2_raw(d[0] - m);
            float p1 = exp2_raw(d[1] - m);
            float p2 = exp2_raw(d[2] - m);
            float p3 = exp2_raw(d[3] - m);
            pk[mt][0] = pkrtz(p0, p1);
            pk[mt][1] = pkrtz(p2, p3);
        }

        // PV + ones-row denominator (both on the MFMA pipe)
        f32x4 o2[2], os;
        o2[0] = (f32x4){0.f, 0.f, 0.f, 0.f};
        o2[1] = (f32x4){0.f, 0.f, 0.f, 0.f};
        os    = (f32x4){0.f, 0.f, 0.f, 0.f};
        __builtin_amdgcn_s_setprio(1);
#pragma unroll
        for (int kc = 0; kc < 16; ++kc) {
            half4 pb = __builtin_bit_cast(half4, pk[kc]);
            half4 av0 = __builtin_bit_cast(half4, *(const sh4*)(vA + kc * 16));
            half4 av1 = __builtin_bit_cast(half4, *(const sh4*)(vA + 4224 + kc * 16));
            o2[0] = mfma_k16(av0, pb, o2[0]);
            o2[1] = mfma_k16(av1, pb, o2[1]);
            os    = mfma_k16(vones, pb, os);
        }
        __builtin_amdgcn_s_setprio(0);
        float inv = 1.0f / os[0];   // column sum for this lane's px

        // write out [b][c*8+h][px] fp32; D row=c=ct*16+q*4+r, col=px
#pragma unroll
        for (int ct = 0; ct < 2; ++ct)
#pragma unroll
            for (int r = 0; r < 4; ++r) {
                int c = ct * 16 + q * 4 + r;
                out[(((long)(b * 256 + c * 8 + h)) << 14) + px] = o2[ct][r] * inv;
            }
    }
}

// ---------------- launch ----------------
extern "C" void kernel_launch(void* const* d_in, const int* in_sizes, int n_in,
                              void* d_out, int out_size, void* d_ws, size_t ws_size,
                              hipStream_t stream) {
    const float* x  = (const float*)d_in[0];
    const float* Wq = (const float*)d_in[1];
    const float* bq = (const float*)d_in[2];
    const float* Wk = (const float*)d_in[3];
    const float* bk = (const float*)d_in[4];
    const float* Wv = (const float*)d_in[5];
    const float* bv = (const float*)d_in[6];
    float* out = (float*)d_out;

    char* ws = (char*)d_ws;
    const size_t OFF_XN = 0;             // 33,554,432  x NHWC f16
    const size_t OFF_Q  = 33554432;      // 33,554,432  q [b][h][px][c] f16 (log2e-scaled)
    const size_t OFF_WP = 67108864;      // 16,777,216  w_pack [512][16384] f16
    const size_t OFF_WQ = 83886080;      //    131,072  wq f16
    const size_t OFF_KP = 84017152;      //    524,288  k_pack f16
    const size_t OFF_VP = 84541440;      //    524,288  v_pack f16
    const size_t OFF_PT = 85065728;      // 16,777,216  partials fp32 [8][1024][512]
    const size_t NEEDED = 118620160;
    if (ws_size < NEEDED) return;        // fail loudly via validation

    short* xn  = (short*)(ws + OFF_XN);
    short* qp  = (short*)(ws + OFF_Q);
    short* wp  = (short*)(ws + OFF_WP);
    short* wqp = (short*)(ws + OFF_WQ);
    short* kp  = (short*)(ws + OFF_KP);
    short* vp  = (short*)(ws + OFF_VP);
    float* part= (float*)(ws + OFF_PT);

    k_pack_x <<<dim3(4096), dim3(256), 0, stream>>>(x, xn);
    k_pack_w <<<dim3(2048), dim3(256), 0, stream>>>(Wk, Wv, wp);
    k_pack_wq<<<dim3(256),  dim3(256), 0, stream>>>(Wq, wqp);
    k_kv_gemm<<<dim3(512),  dim3(256), 0, stream>>>(xn, wp, part);
    k_kv_fin <<<dim3(2048), dim3(256), 0, stream>>>(part, bk, bv, kp, vp);
    k_q_gemm <<<dim3(1024), dim3(256), 0, stream>>>(xn, wqp, bq, qp);
    k_attn   <<<dim3(2048), dim3(256), 0, stream>>>(qp, kp, vp, out);
}